// Round 2
// baseline (424.508 us; speedup 1.0000x reference)
//
#include <hip/hip_runtime.h>
#include <stdint.h>

#define B_   2
#define N_   16384
#define S_   4096
#define D2_  256
#define CIN_ 397
#define KP_  416      // Cin padded to 13*32 for MFMA K-slabs
#define C_   128
#define OC_  13

typedef unsigned short u16;
typedef short s16x8 __attribute__((ext_vector_type(8)));
typedef float f32x4 __attribute__((ext_vector_type(4)));

#define MFMA16(a, b, c) __builtin_amdgcn_mfma_f32_16x16x32_bf16((a), (b), (c), 0, 0, 0)

__device__ __forceinline__ float b2f(u16 h) {
  union { unsigned int u; float f; } v; v.u = ((unsigned int)h) << 16; return v.f;
}
__device__ __forceinline__ u16 f2b(float f) {
  union { float f; unsigned int u; } v; v.f = f;
  unsigned int r = v.u + 0x7fffu + ((v.u >> 16) & 1u);
  return (u16)(r >> 16);
}

// ---------------------------------------------------------------------------
// prep: convert all weights f32->bf16 (pad fuse_W to [128][416], pred2_W to
// [16][128]) and fold BN+bias into per-channel (scale, bias) in f32.
// st layout: st[stage*256 + c] = scale, st[stage*256 + 128 + c] = bias
// ---------------------------------------------------------------------------
__global__ void prep_kernel(const float* __restrict__ fW, const float* __restrict__ fb,
                            const float* __restrict__ fbn,
                            const float* __restrict__ e1W, const float* __restrict__ e1b,
                            const float* __restrict__ e1bn,
                            const float* __restrict__ e2W, const float* __restrict__ e2b,
                            const float* __restrict__ e2bn,
                            const float* __restrict__ p1W, const float* __restrict__ p1b,
                            const float* __restrict__ p1bn,
                            const float* __restrict__ p2W, const float* __restrict__ p2b,
                            const float* __restrict__ p2bn,
                            u16* __restrict__ Wf, u16* __restrict__ W1o,
                            u16* __restrict__ W2o, u16* __restrict__ W3o,
                            u16* __restrict__ Wp2, float* __restrict__ st) {
  int tid = blockIdx.x * 256 + threadIdx.x;
  int stride = gridDim.x * 256;
  for (int i = tid; i < 128 * KP_; i += stride) {
    int m = i / KP_, k = i - m * KP_;
    Wf[i] = (k < CIN_) ? f2b(fW[m * CIN_ + k]) : (u16)0;
  }
  for (int i = tid; i < 128 * 128; i += stride) {
    W1o[i] = f2b(e1W[i]);
    W2o[i] = f2b(e2W[i]);
    W3o[i] = f2b(p1W[i]);
  }
  for (int i = tid; i < 16 * 128; i += stride) {
    int m = i >> 7;
    Wp2[i] = (m < OC_) ? f2b(p2W[i]) : (u16)0;
  }
  for (int i = tid; i < 5 * 128; i += stride) {
    int sg = i >> 7, c = i & 127;
    const float* bn; const float* bc; int Cc = 128;
    switch (sg) {
      case 0: bn = fbn;  bc = fb;  break;
      case 1: bn = e1bn; bc = e1b; break;
      case 2: bn = e2bn; bc = e2b; break;
      case 3: bn = p1bn; bc = p1b; break;
      default: bn = p2bn; bc = p2b; Cc = OC_; break;
    }
    float s = 0.f, t = 0.f;
    if (c < Cc) {
      float g  = bn[0 * Cc + c], be = bn[1 * Cc + c];
      float mu = bn[2 * Cc + c], vv = bn[3 * Cc + c];
      float inv = 1.0f / sqrtf(vv + 1e-5f);
      s = g * inv;
      t = (bc[c] - mu) * s + be;
    }
    st[sg * 256 + c] = s;
    st[sg * 256 + 128 + c] = t;
  }
}

// ---------------------------------------------------------------------------
// tiled transpose, f32 in [b][C][S] -> bf16 out [b][S][opitch] (cols [0,C))
// ---------------------------------------------------------------------------
__global__ void transpose_f2b_kernel(const float* __restrict__ in, u16* __restrict__ out,
                                     int C, int S, int opitch) {
  __shared__ float tile[64][65];
  int b = blockIdx.z;
  int s0 = blockIdx.x * 64, c0 = blockIdx.y * 64;
  const float* ip = in + (size_t)b * C * S;
  u16* op = out + (size_t)b * S * opitch;
  int tr = threadIdx.x >> 4;
  int tc4 = (threadIdx.x & 15) * 4;
#pragma unroll
  for (int r = 0; r < 64; r += 16) {
    float4 v = *(const float4*)(ip + (size_t)(c0 + tr + r) * S + s0 + tc4);
    tile[tr + r][tc4 + 0] = v.x;
    tile[tr + r][tc4 + 1] = v.y;
    tile[tr + r][tc4 + 2] = v.z;
    tile[tr + r][tc4 + 3] = v.w;
  }
  __syncthreads();
#pragma unroll
  for (int r = 0; r < 64; r += 16) {
    ushort4 v;
    v.x = f2b(tile[tc4 + 0][tr + r]);
    v.y = f2b(tile[tc4 + 1][tr + r]);
    v.z = f2b(tile[tc4 + 2][tr + r]);
    v.w = f2b(tile[tc4 + 3][tr + r]);
    *(ushort4*)(op + (size_t)(s0 + tr + r) * opitch + c0 + tc4) = v;
  }
}

// ---------------------------------------------------------------------------
// tiled transpose, f32 in [b][C][S] -> f32 out [b][S][opitch]
// ---------------------------------------------------------------------------
__global__ void transpose_f2f_kernel(const float* __restrict__ in, float* __restrict__ out,
                                     int C, int S, int opitch) {
  __shared__ float tile[64][65];
  int b = blockIdx.z;
  int s0 = blockIdx.x * 64, c0 = blockIdx.y * 64;
  const float* ip = in + (size_t)b * C * S;
  float* op = out + (size_t)b * S * opitch;
  int tr = threadIdx.x >> 4;
  int tc4 = (threadIdx.x & 15) * 4;
#pragma unroll
  for (int r = 0; r < 64; r += 16) {
    float4 v = *(const float4*)(ip + (size_t)(c0 + tr + r) * S + s0 + tc4);
    tile[tr + r][tc4 + 0] = v.x;
    tile[tr + r][tc4 + 1] = v.y;
    tile[tr + r][tc4 + 2] = v.z;
    tile[tr + r][tc4 + 3] = v.w;
  }
  __syncthreads();
#pragma unroll
  for (int r = 0; r < 64; r += 16) {
    float4 v;
    v.x = tile[tc4 + 0][tr + r];
    v.y = tile[tc4 + 1][tr + r];
    v.z = tile[tc4 + 2][tr + r];
    v.w = tile[tc4 + 3][tr + r];
    *(float4*)(op + (size_t)(s0 + tr + r) * opitch + c0 + tc4) = v;
  }
}

// ---------------------------------------------------------------------------
// knn: per (b,n) find 3 smallest squared distances to xyz2.
// f64 math with the reference's exact formula ((n1+n2) - 2*dot, left-assoc),
// stable (d, idx) lexicographic tie-break == top_k semantics.
// ---------------------------------------------------------------------------
__global__ void knn_kernel(const float* __restrict__ xyz1, const float* __restrict__ xyz2,
                           float* __restrict__ wout, int* __restrict__ iout) {
#pragma clang fp contract(off)
  __shared__ float px[S_], py[S_], pz[S_];
  __shared__ double pn[S_];
  __shared__ double md[32][24];
  __shared__ int    mi[32][24];
  int b = blockIdx.y;
  int tid = threadIdx.x;
  const float* x2 = xyz2 + (size_t)b * S_ * 3;
  for (int i = tid; i < S_; i += 256) {
    float xx = x2[i * 3], yy = x2[i * 3 + 1], zz = x2[i * 3 + 2];
    px[i] = xx; py[i] = yy; pz[i] = zz;
    double dx = xx, dy = yy, dz = zz;
    pn[i] = (dx * dx + dy * dy) + dz * dz;
  }
  __syncthreads();
  int q = tid >> 3, sub = tid & 7;
  int n = blockIdx.x * 32 + q;
  const float* x1 = xyz1 + ((size_t)b * N_ + n) * 3;
  double ax = x1[0], ay = x1[1], az = x1[2];
  double n1 = (ax * ax + ay * ay) + az * az;
  double d0 = 1e300, d1 = 1e300, d2 = 1e300;
  int i0 = 0, i1 = 0, i2 = 0;
  for (int it = 0; it < S_ / 8; ++it) {
    int s = it * 8 + sub;
    double dot = (ax * (double)px[s] + ay * (double)py[s]) + az * (double)pz[s];
    double d = (n1 + pn[s]) - 2.0 * dot;
    if (d < d2) {              // strict <: earlier (smaller) index kept on ties
      if (d < d1) {
        d2 = d1; i2 = i1;
        if (d < d0) { d1 = d0; i1 = i0; d0 = d; i0 = s; }
        else        { d1 = d;  i1 = s; }
      } else { d2 = d; i2 = s; }
    }
  }
  md[q][sub * 3 + 0] = d0; mi[q][sub * 3 + 0] = i0;
  md[q][sub * 3 + 1] = d1; mi[q][sub * 3 + 1] = i1;
  md[q][sub * 3 + 2] = d2; mi[q][sub * 3 + 2] = i2;
  __syncthreads();
  if (sub == 0) {
    double D0 = 1e300, D1 = 1e300, D2v = 1e300;
    int I0 = 2147483647, I1 = 2147483647, I2 = 2147483647;
    for (int j = 0; j < 24; ++j) {
      double d = md[q][j]; int i = mi[q][j];
      if ((d < D2v) || (d == D2v && i < I2)) {
        if ((d < D1) || (d == D1 && i < I1)) {
          D2v = D1; I2 = I1;
          if ((d < D0) || (d == D0 && i < I0)) { D1 = D0; I1 = I0; D0 = d; I0 = i; }
          else                                  { D1 = d; I1 = i; }
        } else { D2v = d; I2 = i; }
      }
    }
    double r0 = 1.0 / (D0 + 1e-8);
    double r1 = 1.0 / (D1 + 1e-8);
    double r2 = 1.0 / (D2v + 1e-8);
    double sum = (r0 + r1) + r2;
    size_t o = ((size_t)b * N_ + n) * 3;
    wout[o + 0] = (float)(r0 / sum);
    wout[o + 1] = (float)(r1 / sum);
    wout[o + 2] = (float)(r2 / sum);
    iout[o + 0] = I0; iout[o + 1] = I1; iout[o + 2] = I2;
  }
}

// ---------------------------------------------------------------------------
// interp: fill npT[b][n][128..415] = [interp_pts(256), interp_pred(13), 0 pad]
// one wave per point; f32 row-gathers from p2t (transposed f32), bf16 write
// ---------------------------------------------------------------------------
__global__ void interp_kernel(const float* __restrict__ p2t, const float* __restrict__ last_pred,
                              const float* __restrict__ knw, const int* __restrict__ kni,
                              u16* __restrict__ npT) {
#pragma clang fp contract(off)
  int b = blockIdx.y;
  int n = blockIdx.x * 4 + (threadIdx.x >> 6);
  int lane = threadIdx.x & 63;
  size_t o = ((size_t)b * N_ + n) * 3;
  float w0 = knw[o], w1 = knw[o + 1], w2 = knw[o + 2];
  int i0 = kni[o], i1 = kni[o + 1], i2 = kni[o + 2];
  const float* r0 = p2t + ((size_t)b * S_ + i0) * D2_;
  const float* r1 = p2t + ((size_t)b * S_ + i1) * D2_;
  const float* r2 = p2t + ((size_t)b * S_ + i2) * D2_;
  u16* orow = npT + ((size_t)b * N_ + n) * KP_;
#pragma unroll
  for (int j = 0; j < 4; ++j) {
    int cc = j * 64 + lane;
    float v = (w0 * r0[cc] + w1 * r1[cc]) + w2 * r2[cc];
    orow[128 + cc] = f2b(v);
  }
  const float* lp = last_pred + (size_t)b * S_ * OC_;
  if (lane < OC_) {
    float v = (w0 * lp[i0 * OC_ + lane] + w1 * lp[i1 * OC_ + lane])
              + w2 * lp[i2 * OC_ + lane];
    orow[384 + lane] = f2b(v);
  }
  if (lane < KP_ - CIN_) orow[CIN_ + lane] = 0;
}

// ---------------------------------------------------------------------------
// mega GEMM: fuse -> ext1 -> ext2(+res) -> pred1 -> pred2, one block = 128 pts
// MFMA 16x16x32 bf16; A[m=lane&15][k=(lane>>4)*8+j]; D col=lane&15, row=q*4+r
// ---------------------------------------------------------------------------
__device__ __forceinline__ void gemm_lds128(const u16* __restrict__ W, const u16* xb,
                                            int l15, int lq, int nbase, f32x4 acc[8][2]) {
#pragma unroll
  for (int mt = 0; mt < 8; ++mt) {
    acc[mt][0] = (f32x4){0.f, 0.f, 0.f, 0.f};
    acc[mt][1] = (f32x4){0.f, 0.f, 0.f, 0.f};
  }
  for (int ks = 0; ks < 4; ++ks) {
    int ko = ks * 32 + lq * 8;
    s16x8 b0 = *(const s16x8*)(xb + (nbase + l15) * 136 + ko);
    s16x8 b1 = *(const s16x8*)(xb + (nbase + 16 + l15) * 136 + ko);
#pragma unroll
    for (int mt = 0; mt < 8; ++mt) {
      s16x8 a = *(const s16x8*)(W + (size_t)(mt * 16 + l15) * 128 + ko);
      acc[mt][0] = MFMA16(a, b0, acc[mt][0]);
      acc[mt][1] = MFMA16(a, b1, acc[mt][1]);
    }
  }
}

__global__ __launch_bounds__(256) void mega_kernel(
    const u16* __restrict__ npT, const u16* __restrict__ Wf,
    const u16* __restrict__ W1, const u16* __restrict__ W2,
    const u16* __restrict__ W3, const u16* __restrict__ Wp2,
    const float* __restrict__ st, float* __restrict__ out) {
  __shared__ u16 xb0[128 * 136];
  __shared__ u16 xb1[128 * 136];
  int b = blockIdx.y;
  int n0 = blockIdx.x * 128;
  int tid = threadIdx.x;
  int wv = tid >> 6, lane = tid & 63;
  int l15 = lane & 15, lq = lane >> 4;
  int nbase = wv * 32;
  f32x4 acc[8][2];

  // ---- stage 1: fuse (K=416), B from global npT rows ----
#pragma unroll
  for (int mt = 0; mt < 8; ++mt) {
    acc[mt][0] = (f32x4){0.f, 0.f, 0.f, 0.f};
    acc[mt][1] = (f32x4){0.f, 0.f, 0.f, 0.f};
  }
  {
    const u16* brow0 = npT + ((size_t)(b * N_ + n0 + nbase + l15)) * KP_;
    const u16* brow1 = brow0 + (size_t)16 * KP_;
#pragma unroll 1
    for (int ks = 0; ks < KP_ / 32; ++ks) {
      int ko = ks * 32 + lq * 8;
      s16x8 bf0 = *(const s16x8*)(brow0 + ko);
      s16x8 bf1 = *(const s16x8*)(brow1 + ko);
#pragma unroll
      for (int mt = 0; mt < 8; ++mt) {
        s16x8 a = *(const s16x8*)(Wf + (size_t)(mt * 16 + l15) * KP_ + ko);
        acc[mt][0] = MFMA16(a, bf0, acc[mt][0]);
        acc[mt][1] = MFMA16(a, bf1, acc[mt][1]);
      }
    }
  }
#pragma unroll
  for (int mt = 0; mt < 8; ++mt) {
    f32x4 sc = *(const f32x4*)(st + 0 * 256 + mt * 16 + lq * 4);
    f32x4 bi = *(const f32x4*)(st + 0 * 256 + 128 + mt * 16 + lq * 4);
#pragma unroll
    for (int nt = 0; nt < 2; ++nt) {
      int n_l = nbase + nt * 16 + l15;
      ushort4 v;
      v.x = f2b(fmaxf(acc[mt][nt][0] * sc[0] + bi[0], 0.f));
      v.y = f2b(fmaxf(acc[mt][nt][1] * sc[1] + bi[1], 0.f));
      v.z = f2b(fmaxf(acc[mt][nt][2] * sc[2] + bi[2], 0.f));
      v.w = f2b(fmaxf(acc[mt][nt][3] * sc[3] + bi[3], 0.f));
      *(ushort4*)(&xb0[n_l * 136 + mt * 16 + lq * 4]) = v;
    }
  }
  __syncthreads();

  // ---- stage 2: ext1 (K=128), xb0 -> xb1 ----
  gemm_lds128(W1, xb0, l15, lq, nbase, acc);
#pragma unroll
  for (int mt = 0; mt < 8; ++mt) {
    f32x4 sc = *(const f32x4*)(st + 1 * 256 + mt * 16 + lq * 4);
    f32x4 bi = *(const f32x4*)(st + 1 * 256 + 128 + mt * 16 + lq * 4);
#pragma unroll
    for (int nt = 0; nt < 2; ++nt) {
      int n_l = nbase + nt * 16 + l15;
      ushort4 v;
      v.x = f2b(fmaxf(acc[mt][nt][0] * sc[0] + bi[0], 0.f));
      v.y = f2b(fmaxf(acc[mt][nt][1] * sc[1] + bi[1], 0.f));
      v.z = f2b(fmaxf(acc[mt][nt][2] * sc[2] + bi[2], 0.f));
      v.w = f2b(fmaxf(acc[mt][nt][3] * sc[3] + bi[3], 0.f));
      *(ushort4*)(&xb1[n_l * 136 + mt * 16 + lq * 4]) = v;
    }
  }
  __syncthreads();

  // ---- stage 3: ext2 (K=128), xb1 -> xb0, + residual(xb0), store out0 ----
  gemm_lds128(W2, xb1, l15, lq, nbase, acc);
#pragma unroll
  for (int mt = 0; mt < 8; ++mt) {
    f32x4 sc = *(const f32x4*)(st + 2 * 256 + mt * 16 + lq * 4);
    f32x4 bi = *(const f32x4*)(st + 2 * 256 + 128 + mt * 16 + lq * 4);
#pragma unroll
    for (int nt = 0; nt < 2; ++nt) {
      int n_l = nbase + nt * 16 + l15;
      int n_g = n0 + n_l;
      ushort4 xp = *(const ushort4*)(&xb0[n_l * 136 + mt * 16 + lq * 4]);
      float v0 = fmaxf(acc[mt][nt][0] * sc[0] + bi[0] + b2f(xp.x), 0.f);
      float v1 = fmaxf(acc[mt][nt][1] * sc[1] + bi[1] + b2f(xp.y), 0.f);
      float v2 = fmaxf(acc[mt][nt][2] * sc[2] + bi[2] + b2f(xp.z), 0.f);
      float v3 = fmaxf(acc[mt][nt][3] * sc[3] + bi[3] + b2f(xp.w), 0.f);
      ushort4 v;
      v.x = f2b(v0); v.y = f2b(v1); v.z = f2b(v2); v.w = f2b(v3);
      *(ushort4*)(&xb0[n_l * 136 + mt * 16 + lq * 4]) = v;
      int m = mt * 16 + lq * 4;
      out[((size_t)(b * C_ + m + 0)) * N_ + n_g] = v0;
      out[((size_t)(b * C_ + m + 1)) * N_ + n_g] = v1;
      out[((size_t)(b * C_ + m + 2)) * N_ + n_g] = v2;
      out[((size_t)(b * C_ + m + 3)) * N_ + n_g] = v3;
    }
  }
  __syncthreads();

  // ---- stage 4: pred1 (K=128), xb0 -> xb1, store out1 ([B][N][128]) ----
  gemm_lds128(W3, xb0, l15, lq, nbase, acc);
  {
    float* out1 = out + (size_t)B_ * C_ * N_;
#pragma unroll
    for (int mt = 0; mt < 8; ++mt) {
      f32x4 sc = *(const f32x4*)(st + 3 * 256 + mt * 16 + lq * 4);
      f32x4 bi = *(const f32x4*)(st + 3 * 256 + 128 + mt * 16 + lq * 4);
#pragma unroll
      for (int nt = 0; nt < 2; ++nt) {
        int n_l = nbase + nt * 16 + l15;
        int n_g = n0 + n_l;
        float v0 = fmaxf(acc[mt][nt][0] * sc[0] + bi[0], 0.f);
        float v1 = fmaxf(acc[mt][nt][1] * sc[1] + bi[1], 0.f);
        float v2 = fmaxf(acc[mt][nt][2] * sc[2] + bi[2], 0.f);
        float v3 = fmaxf(acc[mt][nt][3] * sc[3] + bi[3], 0.f);
        ushort4 v;
        v.x = f2b(v0); v.y = f2b(v1); v.z = f2b(v2); v.w = f2b(v3);
        *(ushort4*)(&xb1[n_l * 136 + mt * 16 + lq * 4]) = v;
        float4 o4 = make_float4(v0, v1, v2, v3);
        *(float4*)(out1 + ((size_t)(b * N_ + n_g)) * 128 + mt * 16 + lq * 4) = o4;
      }
    }
  }
  __syncthreads();

  // ---- stage 5: pred2 (M=13 padded 16, K=128), xb1 -> out2 ([B][N][13]) ----
  {
    f32x4 a2[2];
    a2[0] = (f32x4){0.f, 0.f, 0.f, 0.f};
    a2[1] = (f32x4){0.f, 0.f, 0.f, 0.f};
    for (int ks = 0; ks < 4; ++ks) {
      int ko = ks * 32 + lq * 8;
      s16x8 b0 = *(const s16x8*)(&xb1[(nbase + l15) * 136 + ko]);
      s16x8 b1 = *(const s16x8*)(&xb1[(nbase + 16 + l15) * 136 + ko]);
      s16x8 a = *(const s16x8*)(Wp2 + (size_t)l15 * 128 + ko);
      a2[0] = MFMA16(a, b0, a2[0]);
      a2[1] = MFMA16(a, b1, a2[1]);
    }
    float* out2 = out + (size_t)B_ * C_ * N_ + (size_t)B_ * N_ * 128;
    f32x4 sc = *(const f32x4*)(st + 4 * 256 + lq * 4);
    f32x4 bi = *(const f32x4*)(st + 4 * 256 + 128 + lq * 4);
#pragma unroll
    for (int nt = 0; nt < 2; ++nt) {
      int n_g = n0 + nbase + nt * 16 + l15;
#pragma unroll
      for (int r = 0; r < 4; ++r) {
        int m = lq * 4 + r;
        if (m < OC_) {
          out2[((size_t)(b * N_ + n_g)) * OC_ + m] =
              fmaxf(a2[nt][r] * sc[r] + bi[r], 0.f);
        }
      }
    }
  }
}

// ---------------------------------------------------------------------------
extern "C" void kernel_launch(void* const* d_in, const int* in_sizes, int n_in,
                              void* d_out, int out_size, void* d_ws, size_t ws_size,
                              hipStream_t stream) {
  const float* xyz1      = (const float*)d_in[0];
  const float* xyz2      = (const float*)d_in[1];
  const float* points1   = (const float*)d_in[2];
  const float* points2   = (const float*)d_in[3];
  const float* last_pred = (const float*)d_in[4];
  const float* fuse_W    = (const float*)d_in[5];
  const float* fuse_b    = (const float*)d_in[6];
  const float* fuse_bn   = (const float*)d_in[7];
  const float* ext1_W    = (const float*)d_in[8];
  const float* ext1_b    = (const float*)d_in[9];
  const float* ext1_bn   = (const float*)d_in[10];
  const float* ext2_W    = (const float*)d_in[11];
  const float* ext2_b    = (const float*)d_in[12];
  const float* ext2_bn   = (const float*)d_in[13];
  const float* pred1_W   = (const float*)d_in[14];
  const float* pred1_b   = (const float*)d_in[15];
  const float* pred1_bn  = (const float*)d_in[16];
  const float* pred2_W   = (const float*)d_in[17];
  const float* pred2_b   = (const float*)d_in[18];
  const float* pred2_bn  = (const float*)d_in[19];

  char* ws = (char*)d_ws;
  u16*   npT = (u16*)(ws + 0);                 // 2*16384*416*2 = 27,262,976
  float* p2t = (float*)(ws + 27262976);        // 2*4096*256*4  =  8,388,608
  float* knw = (float*)(ws + 35651584);        // 2*16384*3*4   =    393,216
  int*   kni = (int*)(ws + 36044800);          //                   393,216
  u16*   Wf  = (u16*)(ws + 36438016);          // 128*416*2     =    106,496
  u16*   W1  = (u16*)(ws + 36544512);          // 128*128*2     =     32,768
  u16*   W2  = (u16*)(ws + 36577280);          //                     32,768
  u16*   W3  = (u16*)(ws + 36610048);          //                     32,768
  u16*   Wp2 = (u16*)(ws + 36642816);          // 16*128*2      =      4,096
  float* st  = (float*)(ws + 36646912);        // 5*256*4       =      5,120

  prep_kernel<<<dim3(64), dim3(256), 0, stream>>>(
      fuse_W, fuse_b, fuse_bn, ext1_W, ext1_b, ext1_bn, ext2_W, ext2_b, ext2_bn,
      pred1_W, pred1_b, pred1_bn, pred2_W, pred2_b, pred2_bn,
      Wf, W1, W2, W3, Wp2, st);

  // points1 [B][128][N] f32 -> npT[b][n][0..128) bf16, pitch 416
  transpose_f2b_kernel<<<dim3(N_ / 64, 128 / 64, B_), dim3(256), 0, stream>>>(
      points1, npT, 128, N_, KP_);
  // points2 [B][256][S] f32 -> p2t[b][s][0..256) f32, pitch 256
  transpose_f2f_kernel<<<dim3(S_ / 64, 256 / 64, B_), dim3(256), 0, stream>>>(
      points2, p2t, 256, S_, 256);

  knn_kernel<<<dim3(N_ / 32, B_), dim3(256), 0, stream>>>(xyz1, xyz2, knw, kni);

  interp_kernel<<<dim3(N_ / 4, B_), dim3(256), 0, stream>>>(
      p2t, last_pred, knw, kni, npT);

  mega_kernel<<<dim3(N_ / 128, B_), dim3(256), 0, stream>>>(
      npT, Wf, W1, W2, W3, Wp2, st, (float*)d_out);
}

// Round 3
// 255.961 us; speedup vs baseline: 1.6585x; 1.6585x over previous
//
#include <hip/hip_runtime.h>
#include <stdint.h>

#define B_   2
#define N_   16384
#define S_   4096
#define D2_  256
#define CIN_ 397
#define KP_  416      // Cin padded to 13*32 for MFMA K-slabs
#define C_   128
#define OC_  13
#define NCHUNK_ 8
#define CHS_ (S_ / NCHUNK_)   // 512 points per scan chunk

typedef unsigned short u16;
typedef short s16x8 __attribute__((ext_vector_type(8)));
typedef float f32x4 __attribute__((ext_vector_type(4)));

#define MFMA16(a, b, c) __builtin_amdgcn_mfma_f32_16x16x32_bf16((a), (b), (c), 0, 0, 0)

__device__ __forceinline__ float b2f(u16 h) {
  union { unsigned int u; float f; } v; v.u = ((unsigned int)h) << 16; return v.f;
}
__device__ __forceinline__ u16 f2b(float f) {
  union { float f; unsigned int u; } v; v.f = f;
  unsigned int r = v.u + 0x7fffu + ((v.u >> 16) & 1u);
  return (u16)(r >> 16);
}

// ---------------------------------------------------------------------------
// prep: convert all weights f32->bf16 (pad fuse_W to [128][416], pred2_W to
// [16][128]) and fold BN+bias into per-channel (scale, bias) in f32.
// ---------------------------------------------------------------------------
__global__ void prep_kernel(const float* __restrict__ fW, const float* __restrict__ fb,
                            const float* __restrict__ fbn,
                            const float* __restrict__ e1W, const float* __restrict__ e1b,
                            const float* __restrict__ e1bn,
                            const float* __restrict__ e2W, const float* __restrict__ e2b,
                            const float* __restrict__ e2bn,
                            const float* __restrict__ p1W, const float* __restrict__ p1b,
                            const float* __restrict__ p1bn,
                            const float* __restrict__ p2W, const float* __restrict__ p2b,
                            const float* __restrict__ p2bn,
                            u16* __restrict__ Wf, u16* __restrict__ W1o,
                            u16* __restrict__ W2o, u16* __restrict__ W3o,
                            u16* __restrict__ Wp2, float* __restrict__ st) {
  int tid = blockIdx.x * 256 + threadIdx.x;
  int stride = gridDim.x * 256;
  for (int i = tid; i < 128 * KP_; i += stride) {
    int m = i / KP_, k = i - m * KP_;
    Wf[i] = (k < CIN_) ? f2b(fW[m * CIN_ + k]) : (u16)0;
  }
  for (int i = tid; i < 128 * 128; i += stride) {
    W1o[i] = f2b(e1W[i]);
    W2o[i] = f2b(e2W[i]);
    W3o[i] = f2b(p1W[i]);
  }
  for (int i = tid; i < 16 * 128; i += stride) {
    int m = i >> 7;
    Wp2[i] = (m < OC_) ? f2b(p2W[i]) : (u16)0;
  }
  for (int i = tid; i < 5 * 128; i += stride) {
    int sg = i >> 7, c = i & 127;
    const float* bn; const float* bc; int Cc = 128;
    switch (sg) {
      case 0: bn = fbn;  bc = fb;  break;
      case 1: bn = e1bn; bc = e1b; break;
      case 2: bn = e2bn; bc = e2b; break;
      case 3: bn = p1bn; bc = p1b; break;
      default: bn = p2bn; bc = p2b; Cc = OC_; break;
    }
    float s = 0.f, t = 0.f;
    if (c < Cc) {
      float g  = bn[0 * Cc + c], be = bn[1 * Cc + c];
      float mu = bn[2 * Cc + c], vv = bn[3 * Cc + c];
      float inv = 1.0f / sqrtf(vv + 1e-5f);
      s = g * inv;
      t = (bc[c] - mu) * s + be;
    }
    st[sg * 256 + c] = s;
    st[sg * 256 + 128 + c] = t;
  }
}

// ---------------------------------------------------------------------------
// tiled transpose, f32 in [b][C][S] -> bf16 out [b][S][opitch] (cols [0,C))
// ---------------------------------------------------------------------------
__global__ void transpose_f2b_kernel(const float* __restrict__ in, u16* __restrict__ out,
                                     int C, int S, int opitch) {
  __shared__ float tile[64][65];
  int b = blockIdx.z;
  int s0 = blockIdx.x * 64, c0 = blockIdx.y * 64;
  const float* ip = in + (size_t)b * C * S;
  u16* op = out + (size_t)b * S * opitch;
  int tr = threadIdx.x >> 4;
  int tc4 = (threadIdx.x & 15) * 4;
#pragma unroll
  for (int r = 0; r < 64; r += 16) {
    float4 v = *(const float4*)(ip + (size_t)(c0 + tr + r) * S + s0 + tc4);
    tile[tr + r][tc4 + 0] = v.x;
    tile[tr + r][tc4 + 1] = v.y;
    tile[tr + r][tc4 + 2] = v.z;
    tile[tr + r][tc4 + 3] = v.w;
  }
  __syncthreads();
#pragma unroll
  for (int r = 0; r < 64; r += 16) {
    ushort4 v;
    v.x = f2b(tile[tc4 + 0][tr + r]);
    v.y = f2b(tile[tc4 + 1][tr + r]);
    v.z = f2b(tile[tc4 + 2][tr + r]);
    v.w = f2b(tile[tc4 + 3][tr + r]);
    *(ushort4*)(op + (size_t)(s0 + tr + r) * opitch + c0 + tc4) = v;
  }
}

// ---------------------------------------------------------------------------
// knn_scan: f32 candidate scan. Grid (NCHUNK_, N_/256, B_), block 256.
// Each thread owns one query, scans a 512-point chunk staged in LDS (float4,
// broadcast reads), keeps top-4 (strict <, earliest index on ties).
// Emits candidate indices only (u16); f64 refine happens in knn_merge.
// ---------------------------------------------------------------------------
__global__ __launch_bounds__(256) void knn_scan_kernel(
    const float* __restrict__ xyz1, const float* __restrict__ xyz2,
    u16* __restrict__ cand) {
  __shared__ float4 pts[CHS_];
  int b = blockIdx.z;
  int chunk = blockIdx.x;
  int s0 = chunk * CHS_;
  int tid = threadIdx.x;
  const float* x2 = xyz2 + ((size_t)b * S_ + s0) * 3;
  for (int i = tid; i < CHS_; i += 256) {
    float xx = x2[i * 3], yy = x2[i * 3 + 1], zz = x2[i * 3 + 2];
    pts[i] = make_float4(xx, yy, zz, fmaf(xx, xx, fmaf(yy, yy, zz * zz)));
  }
  __syncthreads();
  int n = blockIdx.y * 256 + tid;
  const float* x1 = xyz1 + ((size_t)b * N_ + n) * 3;
  float ax = x1[0], ay = x1[1], az = x1[2];
  float n1 = fmaf(ax, ax, fmaf(ay, ay, az * az));
  float d0 = 3.4e38f, d1 = 3.4e38f, d2 = 3.4e38f, d3 = 3.4e38f;
  int i0 = 0, i1 = 0, i2 = 0, i3 = 0;
#pragma unroll 4
  for (int s = 0; s < CHS_; ++s) {
    float4 p = pts[s];
    float dot = fmaf(ax, p.x, fmaf(ay, p.y, az * p.z));
    float d = fmaf(-2.f, dot, n1 + p.w);
    if (d < d3) {
      int g = s0 + s;
      if (d < d1) {
        d3 = d2; i3 = i2; d2 = d1; i2 = i1;
        if (d < d0) { d1 = d0; i1 = i0; d0 = d; i0 = g; }
        else        { d1 = d; i1 = g; }
      } else {
        if (d < d2) { d3 = d2; i3 = i2; d2 = d; i2 = g; }
        else        { d3 = d; i3 = g; }
      }
    }
  }
  u16* co = cand + ((size_t)(b * N_ + n)) * (NCHUNK_ * 4) + chunk * 4;
  co[0] = (u16)i0; co[1] = (u16)i1; co[2] = (u16)i2; co[3] = (u16)i3;
}

// ---------------------------------------------------------------------------
// knn_merge: per query, recompute all 32 candidate distances in f64 with the
// reference's exact formula ((n1+n2) - 2*dot, left-assoc, contract off),
// select top-3 by lexicographic (d, idx)  == stable top_k semantics,
// compute interpolation weights in f64 (matches R2's passing kernel).
// ---------------------------------------------------------------------------
__global__ void knn_merge_kernel(const float* __restrict__ xyz1,
                                 const float* __restrict__ xyz2,
                                 const u16* __restrict__ cand,
                                 float* __restrict__ wout, int* __restrict__ iout) {
#pragma clang fp contract(off)
  int q = blockIdx.x * 256 + threadIdx.x;   // 0 .. B_*N_-1
  int b = q >> 14;
  const u16* ci = cand + (size_t)q * (NCHUNK_ * 4);
  const float* x1 = xyz1 + (size_t)q * 3;
  double ax = x1[0], ay = x1[1], az = x1[2];
  double n1 = (ax * ax + ay * ay) + az * az;
  const float* x2b = xyz2 + (size_t)b * S_ * 3;
  double D0 = 1e300, D1 = 1e300, D2v = 1e300;
  int I0 = 2147483647, I1 = 2147483647, I2 = 2147483647;
  for (int j = 0; j < NCHUNK_ * 4; ++j) {
    int i = ci[j];
    const float* p = x2b + (size_t)i * 3;
    double px = p[0], py = p[1], pz = p[2];
    double n2 = (px * px + py * py) + pz * pz;
    double dot = (ax * px + ay * py) + az * pz;
    double d = (n1 + n2) - 2.0 * dot;
    if ((d < D2v) || (d == D2v && i < I2)) {
      if ((d < D1) || (d == D1 && i < I1)) {
        D2v = D1; I2 = I1;
        if ((d < D0) || (d == D0 && i < I0)) { D1 = D0; I1 = I0; D0 = d; I0 = i; }
        else                                  { D1 = d; I1 = i; }
      } else { D2v = d; I2 = i; }
    }
  }
  double r0 = 1.0 / (D0 + 1e-8);
  double r1 = 1.0 / (D1 + 1e-8);
  double r2 = 1.0 / (D2v + 1e-8);
  double sum = (r0 + r1) + r2;
  size_t o = (size_t)q * 3;
  wout[o + 0] = (float)(r0 / sum);
  wout[o + 1] = (float)(r1 / sum);
  wout[o + 2] = (float)(r2 / sum);
  iout[o + 0] = I0; iout[o + 1] = I1; iout[o + 2] = I2;
}

// ---------------------------------------------------------------------------
// interp: fill npT[b][n][128..415] = [interp_pts(256), interp_pred(13), 0 pad]
// one wave per point; ushort4 row-gathers from bf16 p2t
// ---------------------------------------------------------------------------
__global__ void interp_kernel(const u16* __restrict__ p2t, const float* __restrict__ last_pred,
                              const float* __restrict__ knw, const int* __restrict__ kni,
                              u16* __restrict__ npT) {
#pragma clang fp contract(off)
  int b = blockIdx.y;
  int n = blockIdx.x * 4 + (threadIdx.x >> 6);
  int lane = threadIdx.x & 63;
  size_t o = ((size_t)b * N_ + n) * 3;
  float w0 = knw[o], w1 = knw[o + 1], w2 = knw[o + 2];
  int i0 = kni[o], i1 = kni[o + 1], i2 = kni[o + 2];
  const u16* r0 = p2t + ((size_t)b * S_ + i0) * D2_;
  const u16* r1 = p2t + ((size_t)b * S_ + i1) * D2_;
  const u16* r2 = p2t + ((size_t)b * S_ + i2) * D2_;
  u16* orow = npT + ((size_t)b * N_ + n) * KP_;
  ushort4 a0 = *(const ushort4*)(r0 + lane * 4);
  ushort4 a1 = *(const ushort4*)(r1 + lane * 4);
  ushort4 a2 = *(const ushort4*)(r2 + lane * 4);
  ushort4 v;
  v.x = f2b((w0 * b2f(a0.x) + w1 * b2f(a1.x)) + w2 * b2f(a2.x));
  v.y = f2b((w0 * b2f(a0.y) + w1 * b2f(a1.y)) + w2 * b2f(a2.y));
  v.z = f2b((w0 * b2f(a0.z) + w1 * b2f(a1.z)) + w2 * b2f(a2.z));
  v.w = f2b((w0 * b2f(a0.w) + w1 * b2f(a1.w)) + w2 * b2f(a2.w));
  *(ushort4*)(orow + 128 + lane * 4) = v;
  const float* lp = last_pred + (size_t)b * S_ * OC_;
  if (lane < OC_) {
    float v2 = (w0 * lp[i0 * OC_ + lane] + w1 * lp[i1 * OC_ + lane])
               + w2 * lp[i2 * OC_ + lane];
    orow[384 + lane] = f2b(v2);
  }
  if (lane < KP_ - CIN_) orow[CIN_ + lane] = 0;
}

// ---------------------------------------------------------------------------
// mega GEMM: fuse -> ext1 -> ext2(+res) -> pred1 -> pred2, one block = 128 pts
// MFMA 16x16x32 bf16; A[m=lane&15][k=(lane>>4)*8+j]; D col=lane&15, row=q*4+r
// ---------------------------------------------------------------------------
__device__ __forceinline__ void gemm_lds128(const u16* __restrict__ W, const u16* xb,
                                            int l15, int lq, int nbase, f32x4 acc[8][2]) {
#pragma unroll
  for (int mt = 0; mt < 8; ++mt) {
    acc[mt][0] = (f32x4){0.f, 0.f, 0.f, 0.f};
    acc[mt][1] = (f32x4){0.f, 0.f, 0.f, 0.f};
  }
  for (int ks = 0; ks < 4; ++ks) {
    int ko = ks * 32 + lq * 8;
    s16x8 b0 = *(const s16x8*)(xb + (nbase + l15) * 136 + ko);
    s16x8 b1 = *(const s16x8*)(xb + (nbase + 16 + l15) * 136 + ko);
#pragma unroll
    for (int mt = 0; mt < 8; ++mt) {
      s16x8 a = *(const s16x8*)(W + (size_t)(mt * 16 + l15) * 128 + ko);
      acc[mt][0] = MFMA16(a, b0, acc[mt][0]);
      acc[mt][1] = MFMA16(a, b1, acc[mt][1]);
    }
  }
}

__global__ __launch_bounds__(256) void mega_kernel(
    const u16* __restrict__ npT, const u16* __restrict__ Wf,
    const u16* __restrict__ W1, const u16* __restrict__ W2,
    const u16* __restrict__ W3, const u16* __restrict__ Wp2,
    const float* __restrict__ st, float* __restrict__ out) {
  __shared__ u16 xb0[128 * 136];
  __shared__ u16 xb1[128 * 136];
  int b = blockIdx.y;
  int n0 = blockIdx.x * 128;
  int tid = threadIdx.x;
  int wv = tid >> 6, lane = tid & 63;
  int l15 = lane & 15, lq = lane >> 4;
  int nbase = wv * 32;
  f32x4 acc[8][2];

  // ---- stage 1: fuse (K=416), B from global npT rows ----
#pragma unroll
  for (int mt = 0; mt < 8; ++mt) {
    acc[mt][0] = (f32x4){0.f, 0.f, 0.f, 0.f};
    acc[mt][1] = (f32x4){0.f, 0.f, 0.f, 0.f};
  }
  {
    const u16* brow0 = npT + ((size_t)(b * N_ + n0 + nbase + l15)) * KP_;
    const u16* brow1 = brow0 + (size_t)16 * KP_;
#pragma unroll 1
    for (int ks = 0; ks < KP_ / 32; ++ks) {
      int ko = ks * 32 + lq * 8;
      s16x8 bf0 = *(const s16x8*)(brow0 + ko);
      s16x8 bf1 = *(const s16x8*)(brow1 + ko);
#pragma unroll
      for (int mt = 0; mt < 8; ++mt) {
        s16x8 a = *(const s16x8*)(Wf + (size_t)(mt * 16 + l15) * KP_ + ko);
        acc[mt][0] = MFMA16(a, bf0, acc[mt][0]);
        acc[mt][1] = MFMA16(a, bf1, acc[mt][1]);
      }
    }
  }
#pragma unroll
  for (int mt = 0; mt < 8; ++mt) {
    f32x4 sc = *(const f32x4*)(st + 0 * 256 + mt * 16 + lq * 4);
    f32x4 bi = *(const f32x4*)(st + 0 * 256 + 128 + mt * 16 + lq * 4);
#pragma unroll
    for (int nt = 0; nt < 2; ++nt) {
      int n_l = nbase + nt * 16 + l15;
      ushort4 v;
      v.x = f2b(fmaxf(acc[mt][nt][0] * sc[0] + bi[0], 0.f));
      v.y = f2b(fmaxf(acc[mt][nt][1] * sc[1] + bi[1], 0.f));
      v.z = f2b(fmaxf(acc[mt][nt][2] * sc[2] + bi[2], 0.f));
      v.w = f2b(fmaxf(acc[mt][nt][3] * sc[3] + bi[3], 0.f));
      *(ushort4*)(&xb0[n_l * 136 + mt * 16 + lq * 4]) = v;
    }
  }
  __syncthreads();

  // ---- stage 2: ext1 (K=128), xb0 -> xb1 ----
  gemm_lds128(W1, xb0, l15, lq, nbase, acc);
#pragma unroll
  for (int mt = 0; mt < 8; ++mt) {
    f32x4 sc = *(const f32x4*)(st + 1 * 256 + mt * 16 + lq * 4);
    f32x4 bi = *(const f32x4*)(st + 1 * 256 + 128 + mt * 16 + lq * 4);
#pragma unroll
    for (int nt = 0; nt < 2; ++nt) {
      int n_l = nbase + nt * 16 + l15;
      ushort4 v;
      v.x = f2b(fmaxf(acc[mt][nt][0] * sc[0] + bi[0], 0.f));
      v.y = f2b(fmaxf(acc[mt][nt][1] * sc[1] + bi[1], 0.f));
      v.z = f2b(fmaxf(acc[mt][nt][2] * sc[2] + bi[2], 0.f));
      v.w = f2b(fmaxf(acc[mt][nt][3] * sc[3] + bi[3], 0.f));
      *(ushort4*)(&xb1[n_l * 136 + mt * 16 + lq * 4]) = v;
    }
  }
  __syncthreads();

  // ---- stage 3: ext2 (K=128), xb1 -> xb0, + residual(xb0), store out0 ----
  gemm_lds128(W2, xb1, l15, lq, nbase, acc);
#pragma unroll
  for (int mt = 0; mt < 8; ++mt) {
    f32x4 sc = *(const f32x4*)(st + 2 * 256 + mt * 16 + lq * 4);
    f32x4 bi = *(const f32x4*)(st + 2 * 256 + 128 + mt * 16 + lq * 4);
#pragma unroll
    for (int nt = 0; nt < 2; ++nt) {
      int n_l = nbase + nt * 16 + l15;
      int n_g = n0 + n_l;
      ushort4 xp = *(const ushort4*)(&xb0[n_l * 136 + mt * 16 + lq * 4]);
      float v0 = fmaxf(acc[mt][nt][0] * sc[0] + bi[0] + b2f(xp.x), 0.f);
      float v1 = fmaxf(acc[mt][nt][1] * sc[1] + bi[1] + b2f(xp.y), 0.f);
      float v2 = fmaxf(acc[mt][nt][2] * sc[2] + bi[2] + b2f(xp.z), 0.f);
      float v3 = fmaxf(acc[mt][nt][3] * sc[3] + bi[3] + b2f(xp.w), 0.f);
      ushort4 v;
      v.x = f2b(v0); v.y = f2b(v1); v.z = f2b(v2); v.w = f2b(v3);
      *(ushort4*)(&xb0[n_l * 136 + mt * 16 + lq * 4]) = v;
      int m = mt * 16 + lq * 4;
      out[((size_t)(b * C_ + m + 0)) * N_ + n_g] = v0;
      out[((size_t)(b * C_ + m + 1)) * N_ + n_g] = v1;
      out[((size_t)(b * C_ + m + 2)) * N_ + n_g] = v2;
      out[((size_t)(b * C_ + m + 3)) * N_ + n_g] = v3;
    }
  }
  __syncthreads();

  // ---- stage 4: pred1 (K=128), xb0 -> xb1, store out1 ([B][N][128]) ----
  gemm_lds128(W3, xb0, l15, lq, nbase, acc);
  {
    float* out1 = out + (size_t)B_ * C_ * N_;
#pragma unroll
    for (int mt = 0; mt < 8; ++mt) {
      f32x4 sc = *(const f32x4*)(st + 3 * 256 + mt * 16 + lq * 4);
      f32x4 bi = *(const f32x4*)(st + 3 * 256 + 128 + mt * 16 + lq * 4);
#pragma unroll
      for (int nt = 0; nt < 2; ++nt) {
        int n_l = nbase + nt * 16 + l15;
        int n_g = n0 + n_l;
        float v0 = fmaxf(acc[mt][nt][0] * sc[0] + bi[0], 0.f);
        float v1 = fmaxf(acc[mt][nt][1] * sc[1] + bi[1], 0.f);
        float v2 = fmaxf(acc[mt][nt][2] * sc[2] + bi[2], 0.f);
        float v3 = fmaxf(acc[mt][nt][3] * sc[3] + bi[3], 0.f);
        ushort4 v;
        v.x = f2b(v0); v.y = f2b(v1); v.z = f2b(v2); v.w = f2b(v3);
        *(ushort4*)(&xb1[n_l * 136 + mt * 16 + lq * 4]) = v;
        float4 o4 = make_float4(v0, v1, v2, v3);
        *(float4*)(out1 + ((size_t)(b * N_ + n_g)) * 128 + mt * 16 + lq * 4) = o4;
      }
    }
  }
  __syncthreads();

  // ---- stage 5: pred2 (M=13 padded 16, K=128), xb1 -> out2 ([B][N][13]) ----
  {
    f32x4 a2[2];
    a2[0] = (f32x4){0.f, 0.f, 0.f, 0.f};
    a2[1] = (f32x4){0.f, 0.f, 0.f, 0.f};
    for (int ks = 0; ks < 4; ++ks) {
      int ko = ks * 32 + lq * 8;
      s16x8 b0 = *(const s16x8*)(&xb1[(nbase + l15) * 136 + ko]);
      s16x8 b1 = *(const s16x8*)(&xb1[(nbase + 16 + l15) * 136 + ko]);
      s16x8 a = *(const s16x8*)(Wp2 + (size_t)l15 * 128 + ko);
      a2[0] = MFMA16(a, b0, a2[0]);
      a2[1] = MFMA16(a, b1, a2[1]);
    }
    float* out2 = out + (size_t)B_ * C_ * N_ + (size_t)B_ * N_ * 128;
    f32x4 sc = *(const f32x4*)(st + 4 * 256 + lq * 4);
    f32x4 bi = *(const f32x4*)(st + 4 * 256 + 128 + lq * 4);
#pragma unroll
    for (int nt = 0; nt < 2; ++nt) {
      int n_g = n0 + nbase + nt * 16 + l15;
#pragma unroll
      for (int r = 0; r < 4; ++r) {
        int m = lq * 4 + r;
        if (m < OC_) {
          out2[((size_t)(b * N_ + n_g)) * OC_ + m] =
              fmaxf(a2[nt][r] * sc[r] + bi[r], 0.f);
        }
      }
    }
  }
}

// ---------------------------------------------------------------------------
extern "C" void kernel_launch(void* const* d_in, const int* in_sizes, int n_in,
                              void* d_out, int out_size, void* d_ws, size_t ws_size,
                              hipStream_t stream) {
  const float* xyz1      = (const float*)d_in[0];
  const float* xyz2      = (const float*)d_in[1];
  const float* points1   = (const float*)d_in[2];
  const float* points2   = (const float*)d_in[3];
  const float* last_pred = (const float*)d_in[4];
  const float* fuse_W    = (const float*)d_in[5];
  const float* fuse_b    = (const float*)d_in[6];
  const float* fuse_bn   = (const float*)d_in[7];
  const float* ext1_W    = (const float*)d_in[8];
  const float* ext1_b    = (const float*)d_in[9];
  const float* ext1_bn   = (const float*)d_in[10];
  const float* ext2_W    = (const float*)d_in[11];
  const float* ext2_b    = (const float*)d_in[12];
  const float* ext2_bn   = (const float*)d_in[13];
  const float* pred1_W   = (const float*)d_in[14];
  const float* pred1_b   = (const float*)d_in[15];
  const float* pred1_bn  = (const float*)d_in[16];
  const float* pred2_W   = (const float*)d_in[17];
  const float* pred2_b   = (const float*)d_in[18];
  const float* pred2_bn  = (const float*)d_in[19];

  char* ws = (char*)d_ws;
  u16*   npT  = (u16*)(ws + 0);                // 2*16384*416*2 = 27,262,976
  u16*   p2t  = (u16*)(ws + 27262976);         // 2*4096*256*2  =  4,194,304
  float* knw  = (float*)(ws + 31457280);       // 2*16384*3*4   =    393,216
  int*   kni  = (int*)(ws + 31850496);         //                    393,216
  u16*   cand = (u16*)(ws + 32243712);         // 2*16384*32*2  =  2,097,152
  u16*   Wf   = (u16*)(ws + 34340864);         // 128*416*2     =    106,496
  u16*   W1   = (u16*)(ws + 34447360);         // 128*128*2     =     32,768
  u16*   W2   = (u16*)(ws + 34480128);         //                     32,768
  u16*   W3   = (u16*)(ws + 34512896);         //                     32,768
  u16*   Wp2  = (u16*)(ws + 34545664);         // 16*128*2      =      4,096
  float* st   = (float*)(ws + 34549760);       // 5*256*4       =      5,120
  // total 34,554,880 <= 36,652,032 proven available in R2

  prep_kernel<<<dim3(64), dim3(256), 0, stream>>>(
      fuse_W, fuse_b, fuse_bn, ext1_W, ext1_b, ext1_bn, ext2_W, ext2_b, ext2_bn,
      pred1_W, pred1_b, pred1_bn, pred2_W, pred2_b, pred2_bn,
      Wf, W1, W2, W3, Wp2, st);

  // points1 [B][128][N] f32 -> npT[b][n][0..128) bf16, pitch 416
  transpose_f2b_kernel<<<dim3(N_ / 64, 128 / 64, B_), dim3(256), 0, stream>>>(
      points1, npT, 128, N_, KP_);
  // points2 [B][256][S] f32 -> p2t[b][s][0..256) bf16, pitch 256
  transpose_f2b_kernel<<<dim3(S_ / 64, 256 / 64, B_), dim3(256), 0, stream>>>(
      points2, p2t, 256, S_, 256);

  knn_scan_kernel<<<dim3(NCHUNK_, N_ / 256, B_), dim3(256), 0, stream>>>(
      xyz1, xyz2, cand);
  knn_merge_kernel<<<dim3(B_ * N_ / 256), dim3(256), 0, stream>>>(
      xyz1, xyz2, cand, knw, kni);

  interp_kernel<<<dim3(N_ / 4, B_), dim3(256), 0, stream>>>(
      p2t, last_pred, knw, kni, npT);

  mega_kernel<<<dim3(N_ / 128, B_), dim3(256), 0, stream>>>(
      npT, Wf, W1, W2, W3, Wp2, st, (float*)d_out);
}

// Round 4
// 231.662 us; speedup vs baseline: 1.8324x; 1.1049x over previous
//
#include <hip/hip_runtime.h>
#include <stdint.h>

#define B_   2
#define N_   16384
#define S_   4096
#define D2_  256
#define CIN_ 397
#define KP_  416      // Cin padded to 13*32 for MFMA K-slabs
#define C_   128
#define OC_  13
#define NCHUNK_ 8
#define CHS_ (S_ / NCHUNK_)   // 512 points per scan chunk

typedef unsigned short u16;
typedef unsigned int u32;
typedef short s16x8 __attribute__((ext_vector_type(8)));
typedef float f32x4 __attribute__((ext_vector_type(4)));

#define MFMA16(a, b, c) __builtin_amdgcn_mfma_f32_16x16x32_bf16((a), (b), (c), 0, 0, 0)

__device__ __forceinline__ float b2f(u16 h) {
  union { unsigned int u; float f; } v; v.u = ((unsigned int)h) << 16; return v.f;
}
__device__ __forceinline__ u16 f2b(float f) {
  union { float f; unsigned int u; } v; v.f = f;
  unsigned int r = v.u + 0x7fffu + ((v.u >> 16) & 1u);
  return (u16)(r >> 16);
}

// ---------------------------------------------------------------------------
// prep: convert all weights f32->bf16 (pad fuse_W to [128][416], pred2_W to
// [16][128]) and fold BN+bias into per-channel (scale, bias) in f32.
// ---------------------------------------------------------------------------
__global__ void prep_kernel(const float* __restrict__ fW, const float* __restrict__ fb,
                            const float* __restrict__ fbn,
                            const float* __restrict__ e1W, const float* __restrict__ e1b,
                            const float* __restrict__ e1bn,
                            const float* __restrict__ e2W, const float* __restrict__ e2b,
                            const float* __restrict__ e2bn,
                            const float* __restrict__ p1W, const float* __restrict__ p1b,
                            const float* __restrict__ p1bn,
                            const float* __restrict__ p2W, const float* __restrict__ p2b,
                            const float* __restrict__ p2bn,
                            u16* __restrict__ Wf, u16* __restrict__ W1o,
                            u16* __restrict__ W2o, u16* __restrict__ W3o,
                            u16* __restrict__ Wp2, float* __restrict__ st) {
  int tid = blockIdx.x * 256 + threadIdx.x;
  int stride = gridDim.x * 256;
  for (int i = tid; i < 128 * KP_; i += stride) {
    int m = i / KP_, k = i - m * KP_;
    Wf[i] = (k < CIN_) ? f2b(fW[m * CIN_ + k]) : (u16)0;
  }
  for (int i = tid; i < 128 * 128; i += stride) {
    W1o[i] = f2b(e1W[i]);
    W2o[i] = f2b(e2W[i]);
    W3o[i] = f2b(p1W[i]);
  }
  for (int i = tid; i < 16 * 128; i += stride) {
    int m = i >> 7;
    Wp2[i] = (m < OC_) ? f2b(p2W[i]) : (u16)0;
  }
  for (int i = tid; i < 5 * 128; i += stride) {
    int sg = i >> 7, c = i & 127;
    const float* bn; const float* bc; int Cc = 128;
    switch (sg) {
      case 0: bn = fbn;  bc = fb;  break;
      case 1: bn = e1bn; bc = e1b; break;
      case 2: bn = e2bn; bc = e2b; break;
      case 3: bn = p1bn; bc = p1b; break;
      default: bn = p2bn; bc = p2b; Cc = OC_; break;
    }
    float s = 0.f, t = 0.f;
    if (c < Cc) {
      float g  = bn[0 * Cc + c], be = bn[1 * Cc + c];
      float mu = bn[2 * Cc + c], vv = bn[3 * Cc + c];
      float inv = 1.0f / sqrtf(vv + 1e-5f);
      s = g * inv;
      t = (bc[c] - mu) * s + be;
    }
    st[sg * 256 + c] = s;
    st[sg * 256 + 128 + c] = t;
  }
}

// ---------------------------------------------------------------------------
// tiled transpose, f32 in [b][C][S] -> bf16 out [b][S][opitch] (cols [0,C))
// ---------------------------------------------------------------------------
__global__ void transpose_f2b_kernel(const float* __restrict__ in, u16* __restrict__ out,
                                     int C, int S, int opitch) {
  __shared__ float tile[64][65];
  int b = blockIdx.z;
  int s0 = blockIdx.x * 64, c0 = blockIdx.y * 64;
  const float* ip = in + (size_t)b * C * S;
  u16* op = out + (size_t)b * S * opitch;
  int tr = threadIdx.x >> 4;
  int tc4 = (threadIdx.x & 15) * 4;
#pragma unroll
  for (int r = 0; r < 64; r += 16) {
    float4 v = *(const float4*)(ip + (size_t)(c0 + tr + r) * S + s0 + tc4);
    tile[tr + r][tc4 + 0] = v.x;
    tile[tr + r][tc4 + 1] = v.y;
    tile[tr + r][tc4 + 2] = v.z;
    tile[tr + r][tc4 + 3] = v.w;
  }
  __syncthreads();
#pragma unroll
  for (int r = 0; r < 64; r += 16) {
    ushort4 v;
    v.x = f2b(tile[tc4 + 0][tr + r]);
    v.y = f2b(tile[tc4 + 1][tr + r]);
    v.z = f2b(tile[tc4 + 2][tr + r]);
    v.w = f2b(tile[tc4 + 3][tr + r]);
    *(ushort4*)(op + (size_t)(s0 + tr + r) * opitch + c0 + tc4) = v;
  }
}

// ---------------------------------------------------------------------------
// knn_scan: branchless f32 candidate scan. Grid (NCHUNK_, N_/256, B_).
// Each thread owns one query, scans a 512-point chunk staged in LDS.
// Key = (f32-bits of d, low 12 mantissa bits cleared) | global point idx.
// Sorted top-4 kept via a 7-op min/max network (no branches, no divergence).
// Quantization (2^-12 rel) can only swap near-equal candidates; f64 merge
// re-orders survivors exactly, so output error stays ~1e-3 max.
// ---------------------------------------------------------------------------
__global__ __launch_bounds__(256) void knn_scan_kernel(
    const float* __restrict__ xyz1, const float* __restrict__ xyz2,
    u16* __restrict__ cand) {
  __shared__ float4 pts[CHS_];
  int b = blockIdx.z;
  int chunk = blockIdx.x;
  int s0 = chunk * CHS_;
  int tid = threadIdx.x;
  const float* x2 = xyz2 + ((size_t)b * S_ + s0) * 3;
  for (int i = tid; i < CHS_; i += 256) {
    float xx = x2[i * 3], yy = x2[i * 3 + 1], zz = x2[i * 3 + 2];
    pts[i] = make_float4(xx, yy, zz, fmaf(xx, xx, fmaf(yy, yy, zz * zz)));
  }
  __syncthreads();
  int n = blockIdx.y * 256 + tid;
  const float* x1 = xyz1 + ((size_t)b * N_ + n) * 3;
  float ax = x1[0], ay = x1[1], az = x1[2];
  float n1 = fmaf(ax, ax, fmaf(ay, ay, az * az));
  u32 k0 = 0xFFFFFFFFu, k1 = 0xFFFFFFFFu, k2 = 0xFFFFFFFFu, k3 = 0xFFFFFFFFu;
#pragma unroll 8
  for (int s = 0; s < CHS_; ++s) {
    float4 p = pts[s];
    float dot = fmaf(ax, p.x, fmaf(ay, p.y, az * p.z));
    float d = fmaf(-2.f, dot, n1 + p.w);
    d = fmaxf(d, 0.f);
    u32 key = (__float_as_uint(d) & 0xFFFFF000u) | (u32)(s0 + s);
    u32 nk0 = min(k0, key);
    u32 nk1 = min(k1, max(k0, key));
    u32 nk2 = min(k2, max(k1, key));
    u32 nk3 = min(k3, max(k2, key));
    k0 = nk0; k1 = nk1; k2 = nk2; k3 = nk3;
  }
  u16* co = cand + ((size_t)(b * N_ + n)) * (NCHUNK_ * 4) + chunk * 4;
  co[0] = (u16)(k0 & 0xFFFu);
  co[1] = (u16)(k1 & 0xFFFu);
  co[2] = (u16)(k2 & 0xFFFu);
  co[3] = (u16)(k3 & 0xFFFu);
}

// ---------------------------------------------------------------------------
// knn_merge: per query, recompute all 32 candidate distances in f64 with the
// reference's exact formula ((n1+n2) - 2*dot, left-assoc, contract off),
// select top-3 by lexicographic (d, idx)  == stable top_k semantics,
// compute interpolation weights in f64.
// ---------------------------------------------------------------------------
__global__ void knn_merge_kernel(const float* __restrict__ xyz1,
                                 const float* __restrict__ xyz2,
                                 const u16* __restrict__ cand,
                                 float* __restrict__ wout, int* __restrict__ iout) {
#pragma clang fp contract(off)
  int q = blockIdx.x * 256 + threadIdx.x;   // 0 .. B_*N_-1
  int b = q >> 14;
  const u16* ci = cand + (size_t)q * (NCHUNK_ * 4);
  const float* x1 = xyz1 + (size_t)q * 3;
  double ax = x1[0], ay = x1[1], az = x1[2];
  double n1 = (ax * ax + ay * ay) + az * az;
  const float* x2b = xyz2 + (size_t)b * S_ * 3;
  double D0 = 1e300, D1 = 1e300, D2v = 1e300;
  int I0 = 2147483647, I1 = 2147483647, I2 = 2147483647;
  for (int j = 0; j < NCHUNK_ * 4; ++j) {
    int i = ci[j];
    const float* p = x2b + (size_t)i * 3;
    double px = p[0], py = p[1], pz = p[2];
    double n2 = (px * px + py * py) + pz * pz;
    double dot = (ax * px + ay * py) + az * pz;
    double d = (n1 + n2) - 2.0 * dot;
    if ((d < D2v) || (d == D2v && i < I2)) {
      if ((d < D1) || (d == D1 && i < I1)) {
        D2v = D1; I2 = I1;
        if ((d < D0) || (d == D0 && i < I0)) { D1 = D0; I1 = I0; D0 = d; I0 = i; }
        else                                  { D1 = d; I1 = i; }
      } else { D2v = d; I2 = i; }
    }
  }
  double r0 = 1.0 / (D0 + 1e-8);
  double r1 = 1.0 / (D1 + 1e-8);
  double r2 = 1.0 / (D2v + 1e-8);
  double sum = (r0 + r1) + r2;
  size_t o = (size_t)q * 3;
  wout[o + 0] = (float)(r0 / sum);
  wout[o + 1] = (float)(r1 / sum);
  wout[o + 2] = (float)(r2 / sum);
  iout[o + 0] = I0; iout[o + 1] = I1; iout[o + 2] = I2;
}

// ---------------------------------------------------------------------------
// interp: fill npT[b][n][128..415] = [interp_pts(256), interp_pred(13), 0 pad]
// one wave per point; ushort4 row-gathers from bf16 p2t
// ---------------------------------------------------------------------------
__global__ void interp_kernel(const u16* __restrict__ p2t, const float* __restrict__ last_pred,
                              const float* __restrict__ knw, const int* __restrict__ kni,
                              u16* __restrict__ npT) {
#pragma clang fp contract(off)
  int b = blockIdx.y;
  int n = blockIdx.x * 4 + (threadIdx.x >> 6);
  int lane = threadIdx.x & 63;
  size_t o = ((size_t)b * N_ + n) * 3;
  float w0 = knw[o], w1 = knw[o + 1], w2 = knw[o + 2];
  int i0 = kni[o], i1 = kni[o + 1], i2 = kni[o + 2];
  const u16* r0 = p2t + ((size_t)b * S_ + i0) * D2_;
  const u16* r1 = p2t + ((size_t)b * S_ + i1) * D2_;
  const u16* r2 = p2t + ((size_t)b * S_ + i2) * D2_;
  u16* orow = npT + ((size_t)b * N_ + n) * KP_;
  ushort4 a0 = *(const ushort4*)(r0 + lane * 4);
  ushort4 a1 = *(const ushort4*)(r1 + lane * 4);
  ushort4 a2 = *(const ushort4*)(r2 + lane * 4);
  ushort4 v;
  v.x = f2b((w0 * b2f(a0.x) + w1 * b2f(a1.x)) + w2 * b2f(a2.x));
  v.y = f2b((w0 * b2f(a0.y) + w1 * b2f(a1.y)) + w2 * b2f(a2.y));
  v.z = f2b((w0 * b2f(a0.z) + w1 * b2f(a1.z)) + w2 * b2f(a2.z));
  v.w = f2b((w0 * b2f(a0.w) + w1 * b2f(a1.w)) + w2 * b2f(a2.w));
  *(ushort4*)(orow + 128 + lane * 4) = v;
  const float* lp = last_pred + (size_t)b * S_ * OC_;
  if (lane < OC_) {
    float v2 = (w0 * lp[i0 * OC_ + lane] + w1 * lp[i1 * OC_ + lane])
               + w2 * lp[i2 * OC_ + lane];
    orow[384 + lane] = f2b(v2);
  }
  if (lane < KP_ - CIN_) orow[CIN_ + lane] = 0;
}

// ---------------------------------------------------------------------------
// mega GEMM: fuse -> ext1 -> ext2(+res) -> pred1 -> pred2, one block = 128 pts
// MFMA 16x16x32 bf16; A[m=lane&15][k=(lane>>4)*8+j]; D col=lane&15, row=q*4+r
// ---------------------------------------------------------------------------
__device__ __forceinline__ void gemm_lds128(const u16* __restrict__ W, const u16* xb,
                                            int l15, int lq, int nbase, f32x4 acc[8][2]) {
#pragma unroll
  for (int mt = 0; mt < 8; ++mt) {
    acc[mt][0] = (f32x4){0.f, 0.f, 0.f, 0.f};
    acc[mt][1] = (f32x4){0.f, 0.f, 0.f, 0.f};
  }
  for (int ks = 0; ks < 4; ++ks) {
    int ko = ks * 32 + lq * 8;
    s16x8 b0 = *(const s16x8*)(xb + (nbase + l15) * 136 + ko);
    s16x8 b1 = *(const s16x8*)(xb + (nbase + 16 + l15) * 136 + ko);
#pragma unroll
    for (int mt = 0; mt < 8; ++mt) {
      s16x8 a = *(const s16x8*)(W + (size_t)(mt * 16 + l15) * 128 + ko);
      acc[mt][0] = MFMA16(a, b0, acc[mt][0]);
      acc[mt][1] = MFMA16(a, b1, acc[mt][1]);
    }
  }
}

__global__ __launch_bounds__(256) void mega_kernel(
    const u16* __restrict__ npT, const u16* __restrict__ Wf,
    const u16* __restrict__ W1, const u16* __restrict__ W2,
    const u16* __restrict__ W3, const u16* __restrict__ Wp2,
    const float* __restrict__ st, float* __restrict__ out) {
  __shared__ u16 xb0[128 * 136];
  __shared__ u16 xb1[128 * 136];
  int b = blockIdx.y;
  int n0 = blockIdx.x * 128;
  int tid = threadIdx.x;
  int wv = tid >> 6, lane = tid & 63;
  int l15 = lane & 15, lq = lane >> 4;
  int nbase = wv * 32;
  f32x4 acc[8][2];

  // ---- stage 1: fuse (K=416), B from global npT rows ----
#pragma unroll
  for (int mt = 0; mt < 8; ++mt) {
    acc[mt][0] = (f32x4){0.f, 0.f, 0.f, 0.f};
    acc[mt][1] = (f32x4){0.f, 0.f, 0.f, 0.f};
  }
  {
    const u16* brow0 = npT + ((size_t)(b * N_ + n0 + nbase + l15)) * KP_;
    const u16* brow1 = brow0 + (size_t)16 * KP_;
#pragma unroll 1
    for (int ks = 0; ks < KP_ / 32; ++ks) {
      int ko = ks * 32 + lq * 8;
      s16x8 bf0 = *(const s16x8*)(brow0 + ko);
      s16x8 bf1 = *(const s16x8*)(brow1 + ko);
#pragma unroll
      for (int mt = 0; mt < 8; ++mt) {
        s16x8 a = *(const s16x8*)(Wf + (size_t)(mt * 16 + l15) * KP_ + ko);
        acc[mt][0] = MFMA16(a, bf0, acc[mt][0]);
        acc[mt][1] = MFMA16(a, bf1, acc[mt][1]);
      }
    }
  }
#pragma unroll
  for (int mt = 0; mt < 8; ++mt) {
    f32x4 sc = *(const f32x4*)(st + 0 * 256 + mt * 16 + lq * 4);
    f32x4 bi = *(const f32x4*)(st + 0 * 256 + 128 + mt * 16 + lq * 4);
#pragma unroll
    for (int nt = 0; nt < 2; ++nt) {
      int n_l = nbase + nt * 16 + l15;
      ushort4 v;
      v.x = f2b(fmaxf(acc[mt][nt][0] * sc[0] + bi[0], 0.f));
      v.y = f2b(fmaxf(acc[mt][nt][1] * sc[1] + bi[1], 0.f));
      v.z = f2b(fmaxf(acc[mt][nt][2] * sc[2] + bi[2], 0.f));
      v.w = f2b(fmaxf(acc[mt][nt][3] * sc[3] + bi[3], 0.f));
      *(ushort4*)(&xb0[n_l * 136 + mt * 16 + lq * 4]) = v;
    }
  }
  __syncthreads();

  // ---- stage 2: ext1 (K=128), xb0 -> xb1 ----
  gemm_lds128(W1, xb0, l15, lq, nbase, acc);
#pragma unroll
  for (int mt = 0; mt < 8; ++mt) {
    f32x4 sc = *(const f32x4*)(st + 1 * 256 + mt * 16 + lq * 4);
    f32x4 bi = *(const f32x4*)(st + 1 * 256 + 128 + mt * 16 + lq * 4);
#pragma unroll
    for (int nt = 0; nt < 2; ++nt) {
      int n_l = nbase + nt * 16 + l15;
      ushort4 v;
      v.x = f2b(fmaxf(acc[mt][nt][0] * sc[0] + bi[0], 0.f));
      v.y = f2b(fmaxf(acc[mt][nt][1] * sc[1] + bi[1], 0.f));
      v.z = f2b(fmaxf(acc[mt][nt][2] * sc[2] + bi[2], 0.f));
      v.w = f2b(fmaxf(acc[mt][nt][3] * sc[3] + bi[3], 0.f));
      *(ushort4*)(&xb1[n_l * 136 + mt * 16 + lq * 4]) = v;
    }
  }
  __syncthreads();

  // ---- stage 3: ext2 (K=128), xb1 -> xb0, + residual(xb0), store out0 ----
  gemm_lds128(W2, xb1, l15, lq, nbase, acc);
#pragma unroll
  for (int mt = 0; mt < 8; ++mt) {
    f32x4 sc = *(const f32x4*)(st + 2 * 256 + mt * 16 + lq * 4);
    f32x4 bi = *(const f32x4*)(st + 2 * 256 + 128 + mt * 16 + lq * 4);
#pragma unroll
    for (int nt = 0; nt < 2; ++nt) {
      int n_l = nbase + nt * 16 + l15;
      int n_g = n0 + n_l;
      ushort4 xp = *(const ushort4*)(&xb0[n_l * 136 + mt * 16 + lq * 4]);
      float v0 = fmaxf(acc[mt][nt][0] * sc[0] + bi[0] + b2f(xp.x), 0.f);
      float v1 = fmaxf(acc[mt][nt][1] * sc[1] + bi[1] + b2f(xp.y), 0.f);
      float v2 = fmaxf(acc[mt][nt][2] * sc[2] + bi[2] + b2f(xp.z), 0.f);
      float v3 = fmaxf(acc[mt][nt][3] * sc[3] + bi[3] + b2f(xp.w), 0.f);
      ushort4 v;
      v.x = f2b(v0); v.y = f2b(v1); v.z = f2b(v2); v.w = f2b(v3);
      *(ushort4*)(&xb0[n_l * 136 + mt * 16 + lq * 4]) = v;
      int m = mt * 16 + lq * 4;
      out[((size_t)(b * C_ + m + 0)) * N_ + n_g] = v0;
      out[((size_t)(b * C_ + m + 1)) * N_ + n_g] = v1;
      out[((size_t)(b * C_ + m + 2)) * N_ + n_g] = v2;
      out[((size_t)(b * C_ + m + 3)) * N_ + n_g] = v3;
    }
  }
  __syncthreads();

  // ---- stage 4: pred1 (K=128), xb0 -> xb1, store out1 ([B][N][128]) ----
  gemm_lds128(W3, xb0, l15, lq, nbase, acc);
  {
    float* out1 = out + (size_t)B_ * C_ * N_;
#pragma unroll
    for (int mt = 0; mt < 8; ++mt) {
      f32x4 sc = *(const f32x4*)(st + 3 * 256 + mt * 16 + lq * 4);
      f32x4 bi = *(const f32x4*)(st + 3 * 256 + 128 + mt * 16 + lq * 4);
#pragma unroll
      for (int nt = 0; nt < 2; ++nt) {
        int n_l = nbase + nt * 16 + l15;
        int n_g = n0 + n_l;
        float v0 = fmaxf(acc[mt][nt][0] * sc[0] + bi[0], 0.f);
        float v1 = fmaxf(acc[mt][nt][1] * sc[1] + bi[1], 0.f);
        float v2 = fmaxf(acc[mt][nt][2] * sc[2] + bi[2], 0.f);
        float v3 = fmaxf(acc[mt][nt][3] * sc[3] + bi[3], 0.f);
        ushort4 v;
        v.x = f2b(v0); v.y = f2b(v1); v.z = f2b(v2); v.w = f2b(v3);
        *(ushort4*)(&xb1[n_l * 136 + mt * 16 + lq * 4]) = v;
        float4 o4 = make_float4(v0, v1, v2, v3);
        *(float4*)(out1 + ((size_t)(b * N_ + n_g)) * 128 + mt * 16 + lq * 4) = o4;
      }
    }
  }
  __syncthreads();

  // ---- stage 5: pred2 (M=13 padded 16, K=128), xb1 -> out2 ([B][N][13]) ----
  {
    f32x4 a2[2];
    a2[0] = (f32x4){0.f, 0.f, 0.f, 0.f};
    a2[1] = (f32x4){0.f, 0.f, 0.f, 0.f};
    for (int ks = 0; ks < 4; ++ks) {
      int ko = ks * 32 + lq * 8;
      s16x8 b0 = *(const s16x8*)(&xb1[(nbase + l15) * 136 + ko]);
      s16x8 b1 = *(const s16x8*)(&xb1[(nbase + 16 + l15) * 136 + ko]);
      s16x8 a = *(const s16x8*)(Wp2 + (size_t)l15 * 128 + ko);
      a2[0] = MFMA16(a, b0, a2[0]);
      a2[1] = MFMA16(a, b1, a2[1]);
    }
    float* out2 = out + (size_t)B_ * C_ * N_ + (size_t)B_ * N_ * 128;
    f32x4 sc = *(const f32x4*)(st + 4 * 256 + lq * 4);
    f32x4 bi = *(const f32x4*)(st + 4 * 256 + 128 + lq * 4);
#pragma unroll
    for (int nt = 0; nt < 2; ++nt) {
      int n_g = n0 + nbase + nt * 16 + l15;
#pragma unroll
      for (int r = 0; r < 4; ++r) {
        int m = lq * 4 + r;
        if (m < OC_) {
          out2[((size_t)(b * N_ + n_g)) * OC_ + m] =
              fmaxf(a2[nt][r] * sc[r] + bi[r], 0.f);
        }
      }
    }
  }
}

// ---------------------------------------------------------------------------
extern "C" void kernel_launch(void* const* d_in, const int* in_sizes, int n_in,
                              void* d_out, int out_size, void* d_ws, size_t ws_size,
                              hipStream_t stream) {
  const float* xyz1      = (const float*)d_in[0];
  const float* xyz2      = (const float*)d_in[1];
  const float* points1   = (const float*)d_in[2];
  const float* points2   = (const float*)d_in[3];
  const float* last_pred = (const float*)d_in[4];
  const float* fuse_W    = (const float*)d_in[5];
  const float* fuse_b    = (const float*)d_in[6];
  const float* fuse_bn   = (const float*)d_in[7];
  const float* ext1_W    = (const float*)d_in[8];
  const float* ext1_b    = (const float*)d_in[9];
  const float* ext1_bn   = (const float*)d_in[10];
  const float* ext2_W    = (const float*)d_in[11];
  const float* ext2_b    = (const float*)d_in[12];
  const float* ext2_bn   = (const float*)d_in[13];
  const float* pred1_W   = (const float*)d_in[14];
  const float* pred1_b   = (const float*)d_in[15];
  const float* pred1_bn  = (const float*)d_in[16];
  const float* pred2_W   = (const float*)d_in[17];
  const float* pred2_b   = (const float*)d_in[18];
  const float* pred2_bn  = (const float*)d_in[19];

  char* ws = (char*)d_ws;
  u16*   npT  = (u16*)(ws + 0);                // 2*16384*416*2 = 27,262,976
  u16*   p2t  = (u16*)(ws + 27262976);         // 2*4096*256*2  =  4,194,304
  float* knw  = (float*)(ws + 31457280);       // 2*16384*3*4   =    393,216
  int*   kni  = (int*)(ws + 31850496);         //                    393,216
  u16*   cand = (u16*)(ws + 32243712);         // 2*16384*32*2  =  2,097,152
  u16*   Wf   = (u16*)(ws + 34340864);         // 128*416*2     =    106,496
  u16*   W1   = (u16*)(ws + 34447360);         // 128*128*2     =     32,768
  u16*   W2   = (u16*)(ws + 34480128);         //                     32,768
  u16*   W3   = (u16*)(ws + 34512896);         //                     32,768
  u16*   Wp2  = (u16*)(ws + 34545664);         // 16*128*2      =      4,096
  float* st   = (float*)(ws + 34549760);       // 5*256*4       =      5,120

  prep_kernel<<<dim3(64), dim3(256), 0, stream>>>(
      fuse_W, fuse_b, fuse_bn, ext1_W, ext1_b, ext1_bn, ext2_W, ext2_b, ext2_bn,
      pred1_W, pred1_b, pred1_bn, pred2_W, pred2_b, pred2_bn,
      Wf, W1, W2, W3, Wp2, st);

  // points1 [B][128][N] f32 -> npT[b][n][0..128) bf16, pitch 416
  transpose_f2b_kernel<<<dim3(N_ / 64, 128 / 64, B_), dim3(256), 0, stream>>>(
      points1, npT, 128, N_, KP_);
  // points2 [B][256][S] f32 -> p2t[b][s][0..256) bf16, pitch 256
  transpose_f2b_kernel<<<dim3(S_ / 64, 256 / 64, B_), dim3(256), 0, stream>>>(
      points2, p2t, 256, S_, 256);

  knn_scan_kernel<<<dim3(NCHUNK_, N_ / 256, B_), dim3(256), 0, stream>>>(
      xyz1, xyz2, cand);
  knn_merge_kernel<<<dim3(B_ * N_ / 256), dim3(256), 0, stream>>>(
      xyz1, xyz2, cand, knw, kni);

  interp_kernel<<<dim3(N_ / 4, B_), dim3(256), 0, stream>>>(
      p2t, last_pred, knw, kni, npT);

  mega_kernel<<<dim3(N_ / 128, B_), dim3(256), 0, stream>>>(
      npT, Wf, W1, W2, W3, Wp2, st, (float*)d_out);
}